// Round 3
// baseline (419.265 us; speedup 1.0000x reference)
//
#include <hip/hip_runtime.h>
#include <hip/hip_bf16.h>

#define Bdim 64
#define Tdim 96
#define Pdim 256
#define Hdim 128
#define Gdim 512   // 4*H
#define Odim 24
#define BH   32    // batches per block (B split across 2 blocks)
#define WROW 132   // h row length in f16 elems (128+4 pad = 264B rows; 66 dw ≡ 2 mod 32 -> free 2-way bank pattern)

typedef _Float16 f16x8 __attribute__((ext_vector_type(8)));
typedef float    f32x16 __attribute__((ext_vector_type(16)));

union H8 { uint2 u2[2]; unsigned short s[8]; _Float16 h[8]; f16x8 v; };
union HS { _Float16 h; unsigned short s; };

__device__ __forceinline__ float exp2_fast(float x) {
#if __has_builtin(__builtin_amdgcn_exp2f)
    return __builtin_amdgcn_exp2f(x);
#else
    return __expf(x * 0.6931471805599453f);
#endif
}

// Grid: 512 blocks = (point p) x (batch half). 8 waves of 64; wave w owns r' rows
// [64w, 64w+64) via two 32-row MFMA tiles (mt); N=32 batches (this block's half).
// r' = 4*k + gate (i,f,g,o): regs 4q..4q+3 of a lane hold all 4 gates of one (b,k).
// gx fused as 9th MFMA K-step. Gate rows prescaled by log2e (2*log2e for g);
// cell state kept in the 2*log2e-scaled domain.
// Epilogue uses common-denominator forms: 7 transcendentals per (b,k) instead of 10.
__global__ __launch_bounds__(512, 4)
void lstm_fused(const float* __restrict__ x,
                const float* __restrict__ W_ih,
                const float* __restrict__ W_hh,
                const float* __restrict__ b_ih,
                const float* __restrict__ b_hh,
                const float* __restrict__ W_fc,
                const float* __restrict__ b_fc,
                float* __restrict__ out)
{
    __shared__ unsigned short hl[2][BH * WROW];  // double-buffered h (f16 bits)

    const int p    = blockIdx.x >> 1;
    const int half = blockIdx.x & 1;
    const int tid  = threadIdx.x;
    const int w    = tid >> 6;    // wave 0..7
    const int l    = tid & 63;
    const int l31  = l & 31;
    const int hi   = l >> 5;

    const float L1 = 1.4426950408889634f;  // log2(e)
    const float L2 = 2.0f * L1;

    for (int i = tid; i < 2 * BH * WROW; i += 512) ((unsigned short*)hl)[i] = 0;

    // ---- preload A fragments (time-invariant): W_hh rows + gx row, prescaled, f16 ----
    f16x8 afr[2][9];
    #pragma unroll
    for (int mt = 0; mt < 2; ++mt) {
        const int rp   = w * 64 + mt * 32 + l31;       // r'
        const int orow = ((rp & 3) << 7) | (rp >> 2);  // gate*128 + k
        const float sc = ((rp & 3) == 2) ? L2 : L1;    // g gate: 2*log2e
        const float* rowp = W_hh + (size_t)p * Gdim * Hdim + (size_t)orow * Hdim;
        #pragma unroll
        for (int ks = 0; ks < 8; ++ks) {
            int k0 = ks * 16 + hi * 8;
            float4 va = *(const float4*)(rowp + k0);
            float4 vb = *(const float4*)(rowp + k0 + 4);
            H8 u;
            u.h[0] = (_Float16)(sc * va.x); u.h[1] = (_Float16)(sc * va.y);
            u.h[2] = (_Float16)(sc * va.z); u.h[3] = (_Float16)(sc * va.w);
            u.h[4] = (_Float16)(sc * vb.x); u.h[5] = (_Float16)(sc * vb.y);
            u.h[6] = (_Float16)(sc * vb.z); u.h[7] = (_Float16)(sc * vb.w);
            afr[mt][ks] = u.v;
        }
        H8 u9;
        #pragma unroll
        for (int j = 0; j < 8; ++j) u9.s[j] = 0;
        if (hi == 0) {
            u9.h[0] = (_Float16)(sc * W_ih[(size_t)p * Gdim + orow]);            // k=128: * x
            u9.h[1] = (_Float16)(sc * (b_ih[(size_t)p * Gdim + orow] +
                                       b_hh[(size_t)p * Gdim + orow]));          // k=129: * 1
        }
        afr[mt][8] = u9.v;
    }

    float cre[2][4];   // scaled-domain cell state, [mt][q]
    #pragma unroll
    for (int mt = 0; mt < 2; ++mt)
        #pragma unroll
        for (int q = 0; q < 4; ++q) cre[mt][q] = 0.f;

    // x for this lane's batch column b = half*32 + l31 (hi lanes unused for gx)
    const float* xp = x + (size_t)((half * BH + l31) * Tdim) * Pdim + p;
    float xv = xp[0];

    __syncthreads();

    int cur = 0;
    for (int t = 0; t < Tdim; ++t) {
        float xn = (t + 1 < Tdim) ? xp[(size_t)(t + 1) * Pdim] : 0.f;

        f32x16 acc[2];
        #pragma unroll
        for (int j = 0; j < 16; ++j) { acc[0][j] = 0.f; acc[1][j] = 0.f; }

        // GEMM: D[r'][b] += W[r'][k] * h[b][k]; both mt tiles share one B-fragment
        const char* hbase = (const char*)hl[cur];
        #pragma unroll
        for (int ks = 0; ks < 8; ++ks) {
            int boff = l31 * (WROW * 2) + ks * 32 + hi * 16;
            H8 b0;
            b0.u2[0] = *(const uint2*)(hbase + boff);
            b0.u2[1] = *(const uint2*)(hbase + boff + 8);
            acc[0] = __builtin_amdgcn_mfma_f32_32x32x16_f16(afr[0][ks], b0.v, acc[0], 0, 0, 0);
            acc[1] = __builtin_amdgcn_mfma_f32_32x32x16_f16(afr[1][ks], b0.v, acc[1], 0, 0, 0);
        }
        // 9th K-step: gx = x*W_ih + bias
        {
            H8 b0;
            #pragma unroll
            for (int j = 0; j < 8; ++j) b0.s[j] = 0;
            if (hi == 0) { b0.h[0] = (_Float16)xv; b0.h[1] = (_Float16)1.0f; }
            acc[0] = __builtin_amdgcn_mfma_f32_32x32x16_f16(afr[0][8], b0.v, acc[0], 0, 0, 0);
            acc[1] = __builtin_amdgcn_mfma_f32_32x32x16_f16(afr[1][8], b0.v, acc[1], 0, 0, 0);
        }

        // epilogue: regs 4q..4q+3 = gates i,f,g,o of (b=l31, k=16w+8mt+2q+hi)
        unsigned short* hw = hl[cur ^ 1];
        #pragma unroll
        for (int mt = 0; mt < 2; ++mt) {
            #pragma unroll
            for (int q = 0; q < 4; ++q) {
                float yi = acc[mt][4 * q + 0];
                float yf = acc[mt][4 * q + 1];
                float yg = acc[mt][4 * q + 2];   // prescaled by 2*log2e
                float yo = acc[mt][4 * q + 3];
                float Ef = exp2_fast(-yf);
                float Ei = exp2_fast(-yi);
                float Eg = exp2_fast(yg);
                float t1 = 1.0f + Ef;
                float t2 = 1.0f + Ei;
                float t3 = Eg + 1.0f;
                float t4 = Eg - 1.0f;
                float den = (t1 * t2) * t3;
                float ct2 = cre[mt][q] * t2;
                float g4  = L2 * t4;
                float num = __builtin_fmaf(ct2, t3, g4 * t1);
                float cn  = num * __builtin_amdgcn_rcpf(den);
                cn = fminf(60.0f, fmaxf(-60.0f, cn));   // keep exp2(cn) finite
                cre[mt][q] = cn;
                float Eo = exp2_fast(-yo);
                float Ec = exp2_fast(cn);
                float den2 = (1.0f + Eo) * (Ec + 1.0f);
                float hv = (Ec - 1.0f) * __builtin_amdgcn_rcpf(den2);
                HS hs; hs.h = (_Float16)hv;
                int k = w * 16 + mt * 8 + 2 * q + hi;
                hw[l31 * WROW + k] = hs.s;
            }
        }

        __syncthreads();
        cur ^= 1;
        xv = xn;
    }

    // ---- FC: out[b][o][p] = sum_k W_fc[p][o][k]*h[b][k] + b_fc[p][o] ----
    const float* wfc = W_fc + (size_t)p * Odim * Hdim;
    const float* bfc = b_fc + (size_t)p * Odim;
    const unsigned short* hf = hl[cur];
    for (int i = tid; i < BH * Odim; i += 512) {
        int o = i % Odim;
        int b = i / Odim;            // local batch
        float s = bfc[o];
        const float* wr = wfc + o * Hdim;
        const unsigned short* hr = hf + b * WROW;
        #pragma unroll 8
        for (int k2 = 0; k2 < Hdim; ++k2) {
            HS hs; hs.s = hr[k2];
            s = __builtin_fmaf(wr[k2], (float)hs.h, s);
        }
        int bg = half * BH + b;      // global batch
        out[(size_t)bg * Odim * Pdim + (size_t)o * Pdim + p] = s;
    }
}

extern "C" void kernel_launch(void* const* d_in, const int* in_sizes, int n_in,
                              void* d_out, int out_size, void* d_ws, size_t ws_size,
                              hipStream_t stream) {
    const float* x    = (const float*)d_in[0];
    const float* W_ih = (const float*)d_in[1];
    const float* W_hh = (const float*)d_in[2];
    const float* b_ih = (const float*)d_in[3];
    const float* b_hh = (const float*)d_in[4];
    const float* W_fc = (const float*)d_in[5];
    const float* b_fc = (const float*)d_in[6];
    float* out = (float*)d_out;

    lstm_fused<<<dim3(2 * Pdim), dim3(512), 0, stream>>>(x, W_ih, W_hh, b_ih, b_hh, W_fc, b_fc, out);
}

// Round 4
// 400.412 us; speedup vs baseline: 1.0471x; 1.0471x over previous
//
#include <hip/hip_runtime.h>
#include <hip/hip_bf16.h>

#define Bdim 64
#define Tdim 96
#define Pdim 256
#define Hdim 128
#define Gdim 512   // 4*H
#define Odim 24
#define BH   32    // batches per stream (two streams per block)
#define WROW 132   // h row length in f16 elems (128+4 pad = 264B rows; stride 66 dw ≡ 2 mod 32 -> free 2-way bank pattern)

typedef _Float16 f16x8 __attribute__((ext_vector_type(8)));
typedef float    f32x16 __attribute__((ext_vector_type(16)));

union H8 { uint2 u2[2]; unsigned short s[8]; _Float16 h[8]; f16x8 v; };
union HS { _Float16 h; unsigned short s; };

__device__ __forceinline__ float exp2_fast(float x) {
#if __has_builtin(__builtin_amdgcn_exp2f)
    return __builtin_amdgcn_exp2f(x);
#else
    return __expf(x * 0.6931471805599453f);
#endif
}

// One block per point p (grid=256, 1024 threads = 16 waves). Wave w owns r' rows
// [32w, 32w+32); r' = 4*k + gate (i,f,g,o) so regs 4q..4q+3 of a lane hold all 4
// gates of one (b,k). B=64 is split into two streams of 32 batches, software-
// pipelined half a step apart: each phase issues one stream's trans-heavy
// epilogue AND the other stream's MFMA+ds_read chain (independent -> the wave
// scheduler interleaves them, keeping both pipes fed). A-fragments (W_hh,
// prescaled by log2e / 2log2e for g) are shared by both streams: 36 VGPRs.
// gx fused as a 9th MFMA K-step. Cell state kept in 2*log2e-scaled domain;
// common-denominator epilogue: 7 transcendentals per (b,k).
__global__ __launch_bounds__(1024, 4)
void lstm_fused(const float* __restrict__ x,
                const float* __restrict__ W_ih,
                const float* __restrict__ W_hh,
                const float* __restrict__ b_ih,
                const float* __restrict__ b_hh,
                const float* __restrict__ W_fc,
                const float* __restrict__ b_fc,
                float* __restrict__ out)
{
    __shared__ unsigned short hs[2][2][BH * WROW];  // [stream][buf][b*WROW+k], f16 bits

    const int p   = blockIdx.x;
    const int tid = threadIdx.x;
    const int w   = tid >> 6;    // wave 0..15
    const int l31 = tid & 31;
    const int hi  = (tid >> 5) & 1;

    const float L1 = 1.4426950408889634f;  // log2(e)
    const float L2 = 2.0f * L1;

    for (int i = tid; i < 2 * 2 * BH * WROW; i += 1024) ((unsigned short*)hs)[i] = 0;

    // ---- preload shared A fragments (time-invariant): W_hh rows + gx row ----
    f16x8 afr[9];
    {
        const int rp   = w * 32 + l31;                // r'
        const int orow = ((rp & 3) << 7) | (rp >> 2); // gate*128 + k
        const float sc = ((rp & 3) == 2) ? L2 : L1;   // g gate: 2*log2e
        const float* rowp = W_hh + (size_t)p * Gdim * Hdim + (size_t)orow * Hdim;
        #pragma unroll
        for (int ks = 0; ks < 8; ++ks) {
            int k0 = ks * 16 + hi * 8;
            float4 va = *(const float4*)(rowp + k0);
            float4 vb = *(const float4*)(rowp + k0 + 4);
            H8 u;
            u.h[0] = (_Float16)(sc * va.x); u.h[1] = (_Float16)(sc * va.y);
            u.h[2] = (_Float16)(sc * va.z); u.h[3] = (_Float16)(sc * va.w);
            u.h[4] = (_Float16)(sc * vb.x); u.h[5] = (_Float16)(sc * vb.y);
            u.h[6] = (_Float16)(sc * vb.z); u.h[7] = (_Float16)(sc * vb.w);
            afr[ks] = u.v;
        }
        H8 u9;
        #pragma unroll
        for (int j = 0; j < 8; ++j) u9.s[j] = 0;
        if (hi == 0) {
            u9.h[0] = (_Float16)(sc * W_ih[(size_t)p * Gdim + orow]);            // k=128: * x
            u9.h[1] = (_Float16)(sc * (b_ih[(size_t)p * Gdim + orow] +
                                       b_hh[(size_t)p * Gdim + orow]));          // k=129: * 1
        }
        afr[8] = u9.v;
    }

    // GEMM for one stream: D[r'][b] += W[r'][k]*h[b][k], K=128 (+ gx K-step)
    auto do_gemm = [&](const unsigned short* hb, float xv) -> f32x16 {
        f32x16 a;
        #pragma unroll
        for (int j = 0; j < 16; ++j) a[j] = 0.f;
        const char* hbase = (const char*)hb;
        #pragma unroll
        for (int ks = 0; ks < 8; ++ks) {
            int boff = l31 * (WROW * 2) + ks * 32 + hi * 16;
            H8 bb;
            bb.u2[0] = *(const uint2*)(hbase + boff);
            bb.u2[1] = *(const uint2*)(hbase + boff + 8);
            a = __builtin_amdgcn_mfma_f32_32x32x16_f16(afr[ks], bb.v, a, 0, 0, 0);
        }
        H8 bg;
        #pragma unroll
        for (int j = 0; j < 8; ++j) bg.s[j] = 0;
        if (hi == 0) { bg.h[0] = (_Float16)xv; bg.h[1] = (_Float16)1.0f; }
        a = __builtin_amdgcn_mfma_f32_32x32x16_f16(afr[8], bg.v, a, 0, 0, 0);
        return a;
    };

    // epilogue for one stream: gates -> new c (scaled domain), h -> LDS (f16)
    auto do_ep = [&](const f32x16& a, float* cr, unsigned short* hw) {
        #pragma unroll
        for (int q = 0; q < 4; ++q) {
            float yi = a[4 * q + 0];
            float yf = a[4 * q + 1];
            float yg = a[4 * q + 2];   // prescaled by 2*log2e
            float yo = a[4 * q + 3];
            float Ef = exp2_fast(-yf);
            float Ei = exp2_fast(-yi);
            float Eg = exp2_fast(yg);
            float t1 = 1.0f + Ef;
            float t2 = 1.0f + Ei;
            float t3 = Eg + 1.0f;
            float t4 = Eg - 1.0f;
            float den = (t1 * t2) * t3;
            float num = __builtin_fmaf(cr[q] * t2, t3, (L2 * t4) * t1);
            float cn  = num * __builtin_amdgcn_rcpf(den);
            cn = fminf(60.0f, fmaxf(-60.0f, cn));
            cr[q] = cn;
            float Eo = exp2_fast(-yo);
            float Ec = exp2_fast(cn);
            float hv = (Ec - 1.0f) * __builtin_amdgcn_rcpf((1.0f + Eo) * (Ec + 1.0f));
            HS s2; s2.h = (_Float16)hv;
            hw[l31 * WROW + (w * 8 + 2 * q + hi)] = s2.s;
        }
    };

    float cre0[4] = {0.f, 0.f, 0.f, 0.f};
    float cre1[4] = {0.f, 0.f, 0.f, 0.f};

    // x pointers: stream s, lane batch col b = s*BH + l31
    const float* xp0 = x + (size_t)((0 * BH + l31) * Tdim) * Pdim + p;
    const float* xp1 = x + (size_t)((1 * BH + l31) * Tdim) * Pdim + p;
    float xv0 = xp0[0];
    float xv1 = xp1[0];

    __syncthreads();

    int b0 = 0, b1 = 0;
    // prologue: gemm stream0 at t=0
    f32x16 acc0 = do_gemm(hs[0][b0], xv0);
    xv0 = xp0[(size_t)1 * Pdim];      // for gemm0(t=1)

    f32x16 acc1;
    for (int t = 0; t < Tdim; ++t) {
        // phase A: gemm1(t) || ep0(t)
        acc1 = do_gemm(hs[1][b1], xv1);
        do_ep(acc0, cre0, hs[0][b0 ^ 1]);
        __syncthreads();
        b0 ^= 1;
        xv1 = (t + 1 < Tdim) ? xp1[(size_t)(t + 1) * Pdim] : 0.f;

        // phase B: gemm0(t+1) || ep1(t)   (last gemm0 is dead work, harmless)
        acc0 = do_gemm(hs[0][b0], xv0);
        do_ep(acc1, cre1, hs[1][b1 ^ 1]);
        __syncthreads();
        b1 ^= 1;
        xv0 = (t + 2 < Tdim) ? xp0[(size_t)(t + 2) * Pdim] : 0.f;
    }

    // ---- FC: out[b][o][p] = sum_k W_fc[p][o][k]*h[b][k] + b_fc[p][o] ----
    const float* wfc = W_fc + (size_t)p * Odim * Hdim;
    const float* bfc = b_fc + (size_t)p * Odim;
    for (int i = tid; i < Bdim * Odim; i += 1024) {
        int o = i % Odim;
        int b = i / Odim;            // global batch 0..63
        const unsigned short* hr = (b < BH) ? (hs[0][b0] + b * WROW)
                                            : (hs[1][b1] + (b - BH) * WROW);
        float s = bfc[o];
        const float* wr = wfc + o * Hdim;
        #pragma unroll 8
        for (int k2 = 0; k2 < Hdim; ++k2) {
            HS s2; s2.s = hr[k2];
            s = __builtin_fmaf(wr[k2], (float)s2.h, s);
        }
        out[(size_t)b * Odim * Pdim + (size_t)o * Pdim + p] = s;
    }
}

extern "C" void kernel_launch(void* const* d_in, const int* in_sizes, int n_in,
                              void* d_out, int out_size, void* d_ws, size_t ws_size,
                              hipStream_t stream) {
    const float* x    = (const float*)d_in[0];
    const float* W_ih = (const float*)d_in[1];
    const float* W_hh = (const float*)d_in[2];
    const float* b_ih = (const float*)d_in[3];
    const float* b_hh = (const float*)d_in[4];
    const float* W_fc = (const float*)d_in[5];
    const float* b_fc = (const float*)d_in[6];
    float* out = (float*)d_out;

    lstm_fused<<<dim3(Pdim), dim3(1024), 0, stream>>>(x, W_ih, W_hh, b_ih, b_hh, W_fc, b_fc, out);
}